// Round 4
// baseline (542.559 us; speedup 1.0000x reference)
//
#include <hip/hip_runtime.h>
#include <math.h>

// B=4, S=2048, D=1024, H=16, DK=64
#define Bc 4
#define Sc 2048
#define Dc 1024
#define Hc 16
#define DKc 64

typedef __bf16 bf16;
typedef __bf16 bf16x4 __attribute__((ext_vector_type(4)));
typedef __bf16 bf16x8 __attribute__((ext_vector_type(8)));
typedef float  floatx4 __attribute__((ext_vector_type(4)));

__device__ __forceinline__ void load_lds16(const void* g, void* l) {
    __builtin_amdgcn_global_load_lds((const __attribute__((address_space(1))) void*)g,
                                     (__attribute__((address_space(3))) void*)l, 16, 0, 0);
}

#define MFMA16(a, b, c) __builtin_amdgcn_mfma_f32_16x16x32_bf16(a, b, c, 0, 0, 0)

// ---------------------------------------------------------------------------
// bf16 MFMA GEMM body (unchanged from round 3): C = A * W^T + bias
// 128x128 tile, BK=32, 256 threads. MODE 0: fp32 out. MODE 1: bf16 out.
// MODE 2: bf16 transposed out [B][H][DK][S] (V^T).
// ---------------------------------------------------------------------------
template<int MODE>
__device__ __forceinline__ void gemm_body(const bf16* __restrict__ A,
                                          const bf16* __restrict__ W,
                                          const float* __restrict__ bias,
                                          void* __restrict__ out,
                                          bf16* As, bf16* Bs) {
    constexpr int N = Dc, K = Dc;
    const int t  = threadIdx.x;
    const int w  = t >> 6;
    const int l  = t & 63;
    const int m0 = blockIdx.y * 128;
    const int n0 = blockIdx.x * 128;
    const int wm = (w >> 1) * 64;
    const int wn = (w & 1) * 64;
    const int srow = l >> 2;
    const int scol = (l & 3) * 8;
    const int fl = l & 15;
    const int fq = l >> 4;

    floatx4 acc[4][4];
#pragma unroll
    for (int i = 0; i < 4; i++)
#pragma unroll
        for (int j = 0; j < 4; j++)
            acc[i][j] = (floatx4){0.f, 0.f, 0.f, 0.f};

    for (int k0 = 0; k0 < K; k0 += 32) {
#pragma unroll
        for (int i = 0; i < 2; i++) {
            const int inst = w + i * 4;
            load_lds16(A + (size_t)(m0 + inst * 16 + srow) * K + k0 + scol, As + inst * 512);
            load_lds16(W + (size_t)(n0 + inst * 16 + srow) * K + k0 + scol, Bs + inst * 512);
        }
        __syncthreads();

        bf16x8 af[4], bfr[4];
#pragma unroll
        for (int tm = 0; tm < 4; tm++)
            af[tm] = *(const bf16x8*)(As + (wm + tm * 16 + fl) * 32 + fq * 8);
#pragma unroll
        for (int tn = 0; tn < 4; tn++)
            bfr[tn] = *(const bf16x8*)(Bs + (wn + tn * 16 + fl) * 32 + fq * 8);
#pragma unroll
        for (int tm = 0; tm < 4; tm++)
#pragma unroll
            for (int tn = 0; tn < 4; tn++)
                acc[tm][tn] = MFMA16(af[tm], bfr[tn], acc[tm][tn]);
        __syncthreads();
    }

#pragma unroll
    for (int tn = 0; tn < 4; tn++) {
        const int n = n0 + wn + tn * 16 + fl;
        const float bv = bias[n];
#pragma unroll
        for (int tm = 0; tm < 4; tm++) {
            const int mb = m0 + wm + tm * 16 + fq * 4;
            if (MODE == 0) {
                float* O = (float*)out;
#pragma unroll
                for (int r = 0; r < 4; r++)
                    O[(size_t)(mb + r) * N + n] = acc[tm][tn][r] + bv;
            } else if (MODE == 1) {
                bf16* O = (bf16*)out;
#pragma unroll
                for (int r = 0; r < 4; r++)
                    O[(size_t)(mb + r) * N + n] = (bf16)(acc[tm][tn][r] + bv);
            } else {
                const int h = n >> 6, dk = n & 63;
                const int b = mb >> 11, s = mb & 2047;
                bf16* O = (bf16*)out + ((size_t)((b * Hc + h) * DKc + dk)) * Sc + s;
                bf16x4 pk = {(bf16)(acc[tm][tn][0] + bv), (bf16)(acc[tm][tn][1] + bv),
                             (bf16)(acc[tm][tn][2] + bv), (bf16)(acc[tm][tn][3] + bv)};
                *(bf16x4*)O = pk;
            }
        }
    }
}

__global__ __launch_bounds__(256) void gemm_qkv(
    const bf16* __restrict__ Aq, const bf16* __restrict__ Ak, const bf16* __restrict__ Av,
    const bf16* __restrict__ Wqb, const bf16* __restrict__ Wkb, const bf16* __restrict__ Wvb,
    const float* __restrict__ bqs, const float* __restrict__ bk, const float* __restrict__ bv,
    bf16* __restrict__ Oq, bf16* __restrict__ Ok, bf16* __restrict__ Ov) {
    __shared__ bf16 As[128 * 32];
    __shared__ bf16 Bs[128 * 32];
    const int sel = blockIdx.z;
    if (sel == 0)      gemm_body<1>(Aq, Wqb, bqs, Oq, As, Bs);
    else if (sel == 1) gemm_body<1>(Ak, Wkb, bk,  Ok, As, Bs);
    else               gemm_body<2>(Av, Wvb, bv,  Ov, As, Bs);
}

__global__ __launch_bounds__(256) void gemm_out_k(const bf16* __restrict__ A,
                                                  const bf16* __restrict__ W,
                                                  const float* __restrict__ bias,
                                                  float* __restrict__ out) {
    __shared__ bf16 As[128 * 32];
    __shared__ bf16 Bs[128 * 32];
    gemm_body<0>(A, W, bias, out, As, Bs);
}

// ---------------------------------------------------------------------------
// Flash attention, transposed MFMA formulation, fixed-max softmax (-8 bias),
// software-pipelined with NAMED register variables (no arrays -> guaranteed
// VGPR residency; round-3 lambda/array version put fragments in scratch).
// Phase i: QK(i) | prefetch K(i+2) | exp+write P(i)->buf[i%2] |
//          read P(i-1)<-buf[(i-1)%2], PV(i-1) | prefetch V(i+1).
// LDS P round trip spans a full phase; K/V prefetch distance = 2 phases.
// PSTRIDE=40: P reads are single ds_read_b128, 2-way bank aliasing (free).
// ---------------------------------------------------------------------------
#define PSTRIDE 40
#define PBUF0 0
#define PBUF1 (32 * PSTRIDE)

#define LOADK(KS, kt) do {                                                \
    const bf16* _kp = Kb + (size_t)((kt) + fl) * Dc + fq * 8;             \
    KS##0 = *(const bf16x8*)(_kp);                                        \
    KS##1 = *(const bf16x8*)(_kp + 32);                                   \
    KS##2 = *(const bf16x8*)(_kp + 16 * Dc);                              \
    KS##3 = *(const bf16x8*)(_kp + 16 * Dc + 32);                         \
} while (0)

#define LOADV(VS, kt) do {                                                \
    const bf16* _vp = Vb + (size_t)fl * Sc + (kt) + fq * 8;               \
    VS##0 = *(const bf16x8*)(_vp);                                        \
    VS##1 = *(const bf16x8*)(_vp + 16 * Sc);                              \
    VS##2 = *(const bf16x8*)(_vp + 32 * Sc);                              \
    VS##3 = *(const bf16x8*)(_vp + 48 * Sc);                              \
} while (0)

#define QK(KS) do {                                                       \
    floatx4 z;                                                            \
    z = (floatx4){-8.f, -8.f, -8.f, -8.f};                                \
    z = MFMA16(KS##0, q00, z); s00 = MFMA16(KS##1, q01, z);               \
    z = (floatx4){-8.f, -8.f, -8.f, -8.f};                                \
    z = MFMA16(KS##0, q10, z); s01 = MFMA16(KS##1, q11, z);               \
    z = (floatx4){-8.f, -8.f, -8.f, -8.f};                                \
    z = MFMA16(KS##2, q00, z); s10 = MFMA16(KS##3, q01, z);               \
    z = (floatx4){-8.f, -8.f, -8.f, -8.f};                                \
    z = MFMA16(KS##2, q10, z); s11 = MFMA16(KS##3, q11, z);               \
} while (0)

#define EXP1(S, L, OFF) do {                                              \
    float p0 = __expf(S[0]), p1 = __expf(S[1]);                           \
    float p2 = __expf(S[2]), p3 = __expf(S[3]);                           \
    L += (p0 + p1) + (p2 + p3);                                           \
    bf16x4 pk = {(bf16)p0, (bf16)p1, (bf16)p2, (bf16)p3};                 \
    *(bf16x4*)(pwb + (OFF)) = pk;                                         \
} while (0)

#define EXPW(BUF) do {                                                    \
    EXP1(s00, l0, (BUF) + 0 * 16 * PSTRIDE + 0);                          \
    EXP1(s10, l0, (BUF) + 0 * 16 * PSTRIDE + 16);                        \
    EXP1(s01, l1, (BUF) + 1 * 16 * PSTRIDE + 0);                          \
    EXP1(s11, l1, (BUF) + 1 * 16 * PSTRIDE + 16);                        \
} while (0)

#define PV(BUF, VS) do {                                                  \
    bf16x8 pf0 = *(const bf16x8*)(prb + (BUF));                           \
    bf16x8 pf1 = *(const bf16x8*)(prb + (BUF) + 16 * PSTRIDE);            \
    o00 = MFMA16(VS##0, pf0, o00); o01 = MFMA16(VS##0, pf1, o01);         \
    o10 = MFMA16(VS##1, pf0, o10); o11 = MFMA16(VS##1, pf1, o11);         \
    o20 = MFMA16(VS##2, pf0, o20); o21 = MFMA16(VS##2, pf1, o21);         \
    o30 = MFMA16(VS##3, pf0, o30); o31 = MFMA16(VS##3, pf1, o31);         \
} while (0)

__global__ __launch_bounds__(256, 4) void attn_mfma(const bf16* __restrict__ Q,
                                                    const bf16* __restrict__ Kg,
                                                    const bf16* __restrict__ Vt,
                                                    bf16* __restrict__ X) {
    __shared__ bf16 P2[4][2 * 32 * PSTRIDE];

    const int bh = blockIdx.x & 63;
    const int qb = blockIdx.x >> 6;
    const int b = bh >> 4, h = bh & 15;

    const int w  = threadIdx.x >> 6;
    const int l  = threadIdx.x & 63;
    const int fl = l & 15;
    const int fq = l >> 4;
    const int q0i = qb * 128 + w * 32;

    const bf16* Qb = Q  + (size_t)b * Sc * Dc + h * DKc;
    const bf16* Kb = Kg + (size_t)b * Sc * Dc + h * DKc;
    const bf16* Vb = Vt + (size_t)((b * Hc + h) * DKc) * Sc;

    bf16* pwb       = &P2[w][fl * PSTRIDE + fq * 4];
    const bf16* prb = &P2[w][fl * PSTRIDE + fq * 8];

    // persistent Q fragments (q_{qn}{kk})
    bf16x8 q00 = *(const bf16x8*)(Qb + (size_t)(q0i + fl) * Dc + fq * 8);
    bf16x8 q01 = *(const bf16x8*)(Qb + (size_t)(q0i + fl) * Dc + 32 + fq * 8);
    bf16x8 q10 = *(const bf16x8*)(Qb + (size_t)(q0i + 16 + fl) * Dc + fq * 8);
    bf16x8 q11 = *(const bf16x8*)(Qb + (size_t)(q0i + 16 + fl) * Dc + 32 + fq * 8);

    floatx4 o00 = {0.f, 0.f, 0.f, 0.f}, o01 = o00, o10 = o00, o11 = o00;
    floatx4 o20 = o00, o21 = o00, o30 = o00, o31 = o00;
    float l0 = 0.f, l1 = 0.f;
    floatx4 s00, s01, s10, s11;

    bf16x8 kA0, kA1, kA2, kA3, kB0, kB1, kB2, kB3;
    bf16x8 vA0, vA1, vA2, vA3, vB0, vB1, vB2, vB3;

    // prologue
    LOADK(kA, 0);
    LOADK(kB, 32);
    LOADV(vA, 0);

    // phase 0 (no PV)
    QK(kA); LOADK(kA, 64); EXPW(PBUF0); LOADV(vB, 32);
    // phase 1
    QK(kB); LOADK(kB, 96); EXPW(PBUF1); PV(PBUF0, vA); LOADV(vA, 64);

    for (int i = 2; i < 64; i += 2) {
        // even phase i
        QK(kA); LOADK(kA, ((i + 2) & 63) * 32); EXPW(PBUF0);
        PV(PBUF1, vB); LOADV(vB, ((i + 1) & 63) * 32);
        // odd phase i+1
        QK(kB); LOADK(kB, ((i + 3) & 63) * 32); EXPW(PBUF1);
        PV(PBUF0, vA); LOADV(vA, ((i + 2) & 63) * 32);
    }
    // epilogue: PV(63)
    PV(PBUF1, vB);

    // normalize + store (O^T C-layout: row=dk, col=q)
    {
        float lsum = l0;
        lsum += __shfl_xor(lsum, 16);
        lsum += __shfl_xor(lsum, 32);
        const float inv = 1.f / lsum;
        const int q = q0i + fl;
        bf16* xp = X + ((size_t)(b * Sc + q)) * Dc + h * DKc + fq * 4;
        floatx4 o;
        bf16x4 pk;
        o = o00 * inv; pk = (bf16x4){(bf16)o[0], (bf16)o[1], (bf16)o[2], (bf16)o[3]}; *(bf16x4*)(xp)      = pk;
        o = o10 * inv; pk = (bf16x4){(bf16)o[0], (bf16)o[1], (bf16)o[2], (bf16)o[3]}; *(bf16x4*)(xp + 16) = pk;
        o = o20 * inv; pk = (bf16x4){(bf16)o[0], (bf16)o[1], (bf16)o[2], (bf16)o[3]}; *(bf16x4*)(xp + 32) = pk;
        o = o30 * inv; pk = (bf16x4){(bf16)o[0], (bf16)o[1], (bf16)o[2], (bf16)o[3]}; *(bf16x4*)(xp + 48) = pk;
    }
    {
        float lsum = l1;
        lsum += __shfl_xor(lsum, 16);
        lsum += __shfl_xor(lsum, 32);
        const float inv = 1.f / lsum;
        const int q = q0i + 16 + fl;
        bf16* xp = X + ((size_t)(b * Sc + q)) * Dc + h * DKc + fq * 4;
        floatx4 o;
        bf16x4 pk;
        o = o01 * inv; pk = (bf16x4){(bf16)o[0], (bf16)o[1], (bf16)o[2], (bf16)o[3]}; *(bf16x4*)(xp)      = pk;
        o = o11 * inv; pk = (bf16x4){(bf16)o[0], (bf16)o[1], (bf16)o[2], (bf16)o[3]}; *(bf16x4*)(xp + 16) = pk;
        o = o21 * inv; pk = (bf16x4){(bf16)o[0], (bf16)o[1], (bf16)o[2], (bf16)o[3]}; *(bf16x4*)(xp + 32) = pk;
        o = o31 * inv; pk = (bf16x4){(bf16)o[0], (bf16)o[1], (bf16)o[2], (bf16)o[3]}; *(bf16x4*)(xp + 48) = pk;
    }
}

// ---------------------------------------------------------------------------
__global__ __launch_bounds__(256) void cast_qkv(const float* __restrict__ q,
                                                const float* __restrict__ k,
                                                const float* __restrict__ v,
                                                bf16* __restrict__ oq,
                                                bf16* __restrict__ ok,
                                                bf16* __restrict__ ov, int n4) {
    const int sel = blockIdx.z;
    const float* src = sel == 0 ? q : sel == 1 ? k : v;
    bf16* dst = sel == 0 ? oq : sel == 1 ? ok : ov;
    int i = blockIdx.x * 256 + threadIdx.x;
    if (i < n4) {
        const float4 vv = ((const float4*)src)[i];
        bf16x4 o = {(bf16)vv.x, (bf16)vv.y, (bf16)vv.z, (bf16)vv.w};
        ((bf16x4*)dst)[i] = o;
    }
}

__global__ __launch_bounds__(256) void cast_w(const float* __restrict__ wq,
                                              const float* __restrict__ wk,
                                              const float* __restrict__ wv,
                                              const float* __restrict__ wo,
                                              bf16* __restrict__ o0, bf16* __restrict__ o1,
                                              bf16* __restrict__ o2, bf16* __restrict__ o3,
                                              int n4) {
    const int sel = blockIdx.z;
    const float* src = sel == 0 ? wq : sel == 1 ? wk : sel == 2 ? wv : wo;
    bf16* dst = sel == 0 ? o0 : sel == 1 ? o1 : sel == 2 ? o2 : o3;
    const float scale = sel == 0 ? 0.125f : 1.f;
    int i = blockIdx.x * 256 + threadIdx.x;
    if (i < n4) {
        const float4 vv = ((const float4*)src)[i];
        bf16x4 o = {(bf16)(vv.x * scale), (bf16)(vv.y * scale),
                    (bf16)(vv.z * scale), (bf16)(vv.w * scale)};
        ((bf16x4*)dst)[i] = o;
    }
}

__global__ __launch_bounds__(256) void scale_vec(const float* __restrict__ s,
                                                 float* __restrict__ d, int n, float sc) {
    int i = blockIdx.x * 256 + threadIdx.x;
    if (i < n) d[i] = s[i] * sc;
}

// ---------------------------------------------------------------------------
extern "C" void kernel_launch(void* const* d_in, const int* in_sizes, int n_in,
                              void* d_out, int out_size, void* d_ws, size_t ws_size,
                              hipStream_t stream) {
    const float* query = (const float*)d_in[0];
    const float* key_  = (const float*)d_in[1];
    const float* value = (const float*)d_in[2];
    const float* Wq    = (const float*)d_in[3];
    const float* bq    = (const float*)d_in[4];
    const float* Wk    = (const float*)d_in[5];
    const float* bk    = (const float*)d_in[6];
    const float* Wv    = (const float*)d_in[7];
    const float* bv    = (const float*)d_in[8];
    const float* Wo    = (const float*)d_in[9];
    const float* bo    = (const float*)d_in[10];

    const size_t nSD = (size_t)Bc * Sc * Dc;
    const size_t nWW = (size_t)Dc * Dc;

    char* ws = (char*)d_ws;
    bf16* qbf = (bf16*)ws;              ws += nSD * 2;
    bf16* kbf = (bf16*)ws;              ws += nSD * 2;
    bf16* vbf = (bf16*)ws;              ws += nSD * 2;
    bf16* wqb = (bf16*)ws;              ws += nWW * 2;
    bf16* wkb = (bf16*)ws;              ws += nWW * 2;
    bf16* wvb = (bf16*)ws;              ws += nWW * 2;
    bf16* wob = (bf16*)ws;              ws += nWW * 2;
    bf16* Qw  = (bf16*)ws;              ws += nSD * 2;
    bf16* Kw  = (bf16*)ws;              ws += nSD * 2;
    bf16* Vtw = (bf16*)ws;              ws += nSD * 2;
    bf16* Xw  = (bf16*)ws;              ws += nSD * 2;
    float* bqs = (float*)ws;            ws += Dc * 4;

    dim3 gc3((int)(nSD / 4 / 256), 1, 3);
    cast_qkv<<<gc3, 256, 0, stream>>>(query, key_, value, qbf, kbf, vbf, (int)(nSD / 4));
    dim3 gc4((int)(nWW / 4 / 256), 1, 4);
    cast_w<<<gc4, 256, 0, stream>>>(Wq, Wk, Wv, Wo, wqb, wkb, wvb, wob, (int)(nWW / 4));
    scale_vec<<<4, 256, 0, stream>>>(bq, bqs, Dc, 0.125f);

    dim3 ggrid(Dc / 128, Bc * Sc / 128, 3);
    gemm_qkv<<<ggrid, 256, 0, stream>>>(qbf, kbf, vbf, wqb, wkb, wvb,
                                        bqs, bk, bv, Qw, Kw, Vtw);

    attn_mfma<<<(Sc / 128) * Hc * Bc, 256, 0, stream>>>(Qw, Kw, Vtw, Xw);

    dim3 gout(Dc / 128, Bc * Sc / 128);
    gemm_out_k<<<gout, 256, 0, stream>>>(Xw, wob, bo, (float*)d_out);
}

// Round 5
// 387.918 us; speedup vs baseline: 1.3986x; 1.3986x over previous
//
#include <hip/hip_runtime.h>
#include <math.h>

// B=4, S=2048, D=1024, H=16, DK=64
#define Bc 4
#define Sc 2048
#define Dc 1024
#define Hc 16
#define DKc 64

typedef __bf16 bf16;
typedef __bf16 bf16x4 __attribute__((ext_vector_type(4)));
typedef __bf16 bf16x8 __attribute__((ext_vector_type(8)));
typedef float  floatx4 __attribute__((ext_vector_type(4)));

__device__ __forceinline__ void load_lds16(const void* g, void* l) {
    __builtin_amdgcn_global_load_lds((const __attribute__((address_space(1))) void*)g,
                                     (__attribute__((address_space(3))) void*)l, 16, 0, 0);
}

#define MFMA16(a, b, c) __builtin_amdgcn_mfma_f32_16x16x32_bf16(a, b, c, 0, 0, 0)

// ---------------------------------------------------------------------------
// bf16 MFMA GEMM body (unchanged, known-good): C = A * W^T + bias
// 128x128 tile, BK=32, 256 threads. MODE 0: fp32 out. MODE 1: bf16 out.
// MODE 2: bf16 transposed out [B][H][DK][S] (V^T).
// ---------------------------------------------------------------------------
template<int MODE>
__device__ __forceinline__ void gemm_body(const bf16* __restrict__ A,
                                          const bf16* __restrict__ W,
                                          const float* __restrict__ bias,
                                          void* __restrict__ out,
                                          bf16* As, bf16* Bs) {
    constexpr int N = Dc, K = Dc;
    const int t  = threadIdx.x;
    const int w  = t >> 6;
    const int l  = t & 63;
    const int m0 = blockIdx.y * 128;
    const int n0 = blockIdx.x * 128;
    const int wm = (w >> 1) * 64;
    const int wn = (w & 1) * 64;
    const int srow = l >> 2;
    const int scol = (l & 3) * 8;
    const int fl = l & 15;
    const int fq = l >> 4;

    floatx4 acc[4][4];
#pragma unroll
    for (int i = 0; i < 4; i++)
#pragma unroll
        for (int j = 0; j < 4; j++)
            acc[i][j] = (floatx4){0.f, 0.f, 0.f, 0.f};

    for (int k0 = 0; k0 < K; k0 += 32) {
#pragma unroll
        for (int i = 0; i < 2; i++) {
            const int inst = w + i * 4;
            load_lds16(A + (size_t)(m0 + inst * 16 + srow) * K + k0 + scol, As + inst * 512);
            load_lds16(W + (size_t)(n0 + inst * 16 + srow) * K + k0 + scol, Bs + inst * 512);
        }
        __syncthreads();

        bf16x8 af[4], bfr[4];
#pragma unroll
        for (int tm = 0; tm < 4; tm++)
            af[tm] = *(const bf16x8*)(As + (wm + tm * 16 + fl) * 32 + fq * 8);
#pragma unroll
        for (int tn = 0; tn < 4; tn++)
            bfr[tn] = *(const bf16x8*)(Bs + (wn + tn * 16 + fl) * 32 + fq * 8);
#pragma unroll
        for (int tm = 0; tm < 4; tm++)
#pragma unroll
            for (int tn = 0; tn < 4; tn++)
                acc[tm][tn] = MFMA16(af[tm], bfr[tn], acc[tm][tn]);
        __syncthreads();
    }

#pragma unroll
    for (int tn = 0; tn < 4; tn++) {
        const int n = n0 + wn + tn * 16 + fl;
        const float bv = bias[n];
#pragma unroll
        for (int tm = 0; tm < 4; tm++) {
            const int mb = m0 + wm + tm * 16 + fq * 4;
            if (MODE == 0) {
                float* O = (float*)out;
#pragma unroll
                for (int r = 0; r < 4; r++)
                    O[(size_t)(mb + r) * N + n] = acc[tm][tn][r] + bv;
            } else if (MODE == 1) {
                bf16* O = (bf16*)out;
#pragma unroll
                for (int r = 0; r < 4; r++)
                    O[(size_t)(mb + r) * N + n] = (bf16)(acc[tm][tn][r] + bv);
            } else {
                const int h = n >> 6, dk = n & 63;
                const int b = mb >> 11, s = mb & 2047;
                bf16* O = (bf16*)out + ((size_t)((b * Hc + h) * DKc + dk)) * Sc + s;
                bf16x4 pk = {(bf16)(acc[tm][tn][0] + bv), (bf16)(acc[tm][tn][1] + bv),
                             (bf16)(acc[tm][tn][2] + bv), (bf16)(acc[tm][tn][3] + bv)};
                *(bf16x4*)O = pk;
            }
        }
    }
}

__global__ __launch_bounds__(256) void gemm_qkv(
    const bf16* __restrict__ Aq, const bf16* __restrict__ Ak, const bf16* __restrict__ Av,
    const bf16* __restrict__ Wqb, const bf16* __restrict__ Wkb, const bf16* __restrict__ Wvb,
    const float* __restrict__ bqs, const float* __restrict__ bk, const float* __restrict__ bv,
    bf16* __restrict__ Oq, bf16* __restrict__ Ok, bf16* __restrict__ Ov) {
    __shared__ bf16 As[128 * 32];
    __shared__ bf16 Bs[128 * 32];
    const int sel = blockIdx.z;
    if (sel == 0)      gemm_body<1>(Aq, Wqb, bqs, Oq, As, Bs);
    else if (sel == 1) gemm_body<1>(Ak, Wkb, bk,  Ok, As, Bs);
    else               gemm_body<2>(Av, Wvb, bv,  Ov, As, Bs);
}

__global__ __launch_bounds__(256) void gemm_out_k(const bf16* __restrict__ A,
                                                  const bf16* __restrict__ W,
                                                  const float* __restrict__ bias,
                                                  float* __restrict__ out) {
    __shared__ bf16 As[128 * 32];
    __shared__ bf16 Bs[128 * 32];
    gemm_body<0>(A, W, bias, out, As, Bs);
}

// ---------------------------------------------------------------------------
// Flash attention v3: LDS-staged K/V (m97 GEMM structure), fixed-max softmax.
// Block = 128 queries of one (b,h); 4 waves x 32 queries; 32-key phases.
// K tile [32 x 64] and V^T tile [64 x 32] staged once per block per phase via
// global_load_lds (double-buffered, __syncthreads pipeline). XOR-swizzled LDS
// placement (applied by permuting the *source* chunk each lane fetches) makes
// all ds_read_b128 fragment reads bank-uniform:
//   K chunk c of row r  -> slot (c ^ (r&7));  V chunk c of row dk -> (c ^ sv),
//   sv = (dk + dk/4) & 3.
// 16 MFMA/wave per barrier (QK 8 + PV 8). P transpose per-wave, PSTRIDE=36
// (zero conflicts, verified round 3). No per-wave K/V registers -> no spill.
// ---------------------------------------------------------------------------
#define PSTRIDE 36

#define STAGE(d, kt) do {                                                     \
    load_lds16(Kb + (size_t)((kt) + w * 8 + krow) * Dc + kchunk * 8,          \
               &Kbuf[d][w * 512]);                                            \
    load_lds16(Vb + (size_t)(w * 16 + vrow) * Sc + (kt) + vchunk * 8,         \
               &Vbuf[d][w * 512]);                                            \
} while (0)

#define QK(d) do {                                                            \
    bf16x8 kf00 = *(const bf16x8*)&Kbuf[d][fl * 64        + ((fq ^ kx) * 8)];       \
    bf16x8 kf01 = *(const bf16x8*)&Kbuf[d][fl * 64        + (((4 + fq) ^ kx) * 8)]; \
    bf16x8 kf10 = *(const bf16x8*)&Kbuf[d][(16 + fl) * 64 + ((fq ^ kx) * 8)];       \
    bf16x8 kf11 = *(const bf16x8*)&Kbuf[d][(16 + fl) * 64 + (((4 + fq) ^ kx) * 8)]; \
    floatx4 z;                                                                \
    z = (floatx4){-8.f, -8.f, -8.f, -8.f};                                    \
    z = MFMA16(kf00, q00, z); s00 = MFMA16(kf01, q01, z);                     \
    z = (floatx4){-8.f, -8.f, -8.f, -8.f};                                    \
    z = MFMA16(kf00, q10, z); s01 = MFMA16(kf01, q11, z);                     \
    z = (floatx4){-8.f, -8.f, -8.f, -8.f};                                    \
    z = MFMA16(kf10, q00, z); s10 = MFMA16(kf11, q01, z);                     \
    z = (floatx4){-8.f, -8.f, -8.f, -8.f};                                    \
    z = MFMA16(kf10, q10, z); s11 = MFMA16(kf11, q11, z);                     \
} while (0)

#define EXP1(S, L, OFF) do {                                                  \
    float p0 = __expf(S[0]), p1 = __expf(S[1]);                               \
    float p2 = __expf(S[2]), p3 = __expf(S[3]);                               \
    L += (p0 + p1) + (p2 + p3);                                               \
    bf16x4 pk = {(bf16)p0, (bf16)p1, (bf16)p2, (bf16)p3};                     \
    *(bf16x4*)(pwb + (OFF)) = pk;                                             \
} while (0)

#define EXPW() do {                                                           \
    EXP1(s00, l0, 0 * 16 * PSTRIDE + 0);                                      \
    EXP1(s10, l0, 0 * 16 * PSTRIDE + 16);                                     \
    EXP1(s01, l1, 1 * 16 * PSTRIDE + 0);                                      \
    EXP1(s11, l1, 1 * 16 * PSTRIDE + 16);                                     \
} while (0)

#define PV(d) do {                                                            \
    bf16x8 vf0 = *(const bf16x8*)&Vbuf[d][fl * 32        + ((fq ^ svf) * 8)]; \
    bf16x8 vf1 = *(const bf16x8*)&Vbuf[d][(16 + fl) * 32 + ((fq ^ svf) * 8)]; \
    bf16x8 vf2 = *(const bf16x8*)&Vbuf[d][(32 + fl) * 32 + ((fq ^ svf) * 8)]; \
    bf16x8 vf3 = *(const bf16x8*)&Vbuf[d][(48 + fl) * 32 + ((fq ^ svf) * 8)]; \
    bf16x8 pf0 = *(const bf16x8*)(prb);                                       \
    bf16x8 pf1 = *(const bf16x8*)(prb + 16 * PSTRIDE);                        \
    o00 = MFMA16(vf0, pf0, o00); o01 = MFMA16(vf0, pf1, o01);                 \
    o10 = MFMA16(vf1, pf0, o10); o11 = MFMA16(vf1, pf1, o11);                 \
    o20 = MFMA16(vf2, pf0, o20); o21 = MFMA16(vf2, pf1, o21);                 \
    o30 = MFMA16(vf3, pf0, o30); o31 = MFMA16(vf3, pf1, o31);                 \
} while (0)

__global__ __launch_bounds__(256, 3) void attn_mfma(const bf16* __restrict__ Q,
                                                    const bf16* __restrict__ Kg,
                                                    const bf16* __restrict__ Vt,
                                                    bf16* __restrict__ X) {
    __shared__ bf16 Kbuf[2][32 * 64];   // [key][dk], rows swizzled in 16B chunks
    __shared__ bf16 Vbuf[2][64 * 32];   // [dk][key], rows swizzled in 16B chunks
    __shared__ bf16 P2[4][32 * PSTRIDE];

    const int bh = blockIdx.x & 63;
    const int qb = blockIdx.x >> 6;
    const int b = bh >> 4, h = bh & 15;

    const int w  = threadIdx.x >> 6;
    const int l  = threadIdx.x & 63;
    const int fl = l & 15;
    const int fq = l >> 4;
    const int q0i = qb * 128 + w * 32;

    // staging lane roles
    const int krow   = l >> 3;                         // 0..7   (K: 8 rows/wave)
    const int kchunk = (l & 7) ^ krow;                 // swizzled source chunk
    const int vrow   = l >> 2;                         // 0..15  (V: 16 rows/wave)
    const int vchunk = (l & 3) ^ ((vrow + (vrow >> 2)) & 3);
    // fragment-read swizzle keys
    const int kx  = fl & 7;
    const int svf = (fl + (fl >> 2)) & 3;

    const bf16* Qb = Q  + (size_t)b * Sc * Dc + h * DKc;
    const bf16* Kb = Kg + (size_t)b * Sc * Dc + h * DKc;
    const bf16* Vb = Vt + (size_t)((b * Hc + h) * DKc) * Sc;

    bf16* pwb       = &P2[w][fl * PSTRIDE + fq * 4];
    const bf16* prb = &P2[w][fl * PSTRIDE + fq * 8];

    // persistent Q fragments
    bf16x8 q00 = *(const bf16x8*)(Qb + (size_t)(q0i + fl) * Dc + fq * 8);
    bf16x8 q01 = *(const bf16x8*)(Qb + (size_t)(q0i + fl) * Dc + 32 + fq * 8);
    bf16x8 q10 = *(const bf16x8*)(Qb + (size_t)(q0i + 16 + fl) * Dc + fq * 8);
    bf16x8 q11 = *(const bf16x8*)(Qb + (size_t)(q0i + 16 + fl) * Dc + 32 + fq * 8);

    floatx4 o00 = {0.f, 0.f, 0.f, 0.f}, o01 = o00, o10 = o00, o11 = o00;
    floatx4 o20 = o00, o21 = o00, o30 = o00, o31 = o00;
    float l0 = 0.f, l1 = 0.f;
    floatx4 s00, s01, s10, s11;

    STAGE(0, 0);
    __syncthreads();

    for (int kt = 0; kt < Sc; kt += 64) {
        STAGE(1, kt + 32);
        QK(0); EXPW(); PV(0);
        __syncthreads();
        if (kt + 64 < Sc) STAGE(0, kt + 64);
        QK(1); EXPW(); PV(1);
        __syncthreads();
    }

    // normalize + store (O^T C-layout: row=dk, col=q)
    {
        float lsum = l0;
        lsum += __shfl_xor(lsum, 16);
        lsum += __shfl_xor(lsum, 32);
        const float inv = 1.f / lsum;
        bf16* xp = X + ((size_t)(b * Sc + q0i + fl)) * Dc + h * DKc + fq * 4;
        floatx4 o;
        bf16x4 pk;
        o = o00 * inv; pk = (bf16x4){(bf16)o[0], (bf16)o[1], (bf16)o[2], (bf16)o[3]}; *(bf16x4*)(xp)      = pk;
        o = o10 * inv; pk = (bf16x4){(bf16)o[0], (bf16)o[1], (bf16)o[2], (bf16)o[3]}; *(bf16x4*)(xp + 16) = pk;
        o = o20 * inv; pk = (bf16x4){(bf16)o[0], (bf16)o[1], (bf16)o[2], (bf16)o[3]}; *(bf16x4*)(xp + 32) = pk;
        o = o30 * inv; pk = (bf16x4){(bf16)o[0], (bf16)o[1], (bf16)o[2], (bf16)o[3]}; *(bf16x4*)(xp + 48) = pk;
    }
    {
        float lsum = l1;
        lsum += __shfl_xor(lsum, 16);
        lsum += __shfl_xor(lsum, 32);
        const float inv = 1.f / lsum;
        bf16* xp = X + ((size_t)(b * Sc + q0i + 16 + fl)) * Dc + h * DKc + fq * 4;
        floatx4 o;
        bf16x4 pk;
        o = o01 * inv; pk = (bf16x4){(bf16)o[0], (bf16)o[1], (bf16)o[2], (bf16)o[3]}; *(bf16x4*)(xp)      = pk;
        o = o11 * inv; pk = (bf16x4){(bf16)o[0], (bf16)o[1], (bf16)o[2], (bf16)o[3]}; *(bf16x4*)(xp + 16) = pk;
        o = o21 * inv; pk = (bf16x4){(bf16)o[0], (bf16)o[1], (bf16)o[2], (bf16)o[3]}; *(bf16x4*)(xp + 32) = pk;
        o = o31 * inv; pk = (bf16x4){(bf16)o[0], (bf16)o[1], (bf16)o[2], (bf16)o[3]}; *(bf16x4*)(xp + 48) = pk;
    }
}

// ---------------------------------------------------------------------------
__global__ __launch_bounds__(256) void cast_qkv(const float* __restrict__ q,
                                                const float* __restrict__ k,
                                                const float* __restrict__ v,
                                                bf16* __restrict__ oq,
                                                bf16* __restrict__ ok,
                                                bf16* __restrict__ ov, int n4) {
    const int sel = blockIdx.z;
    const float* src = sel == 0 ? q : sel == 1 ? k : v;
    bf16* dst = sel == 0 ? oq : sel == 1 ? ok : ov;
    int i = blockIdx.x * 256 + threadIdx.x;
    if (i < n4) {
        const float4 vv = ((const float4*)src)[i];
        bf16x4 o = {(bf16)vv.x, (bf16)vv.y, (bf16)vv.z, (bf16)vv.w};
        ((bf16x4*)dst)[i] = o;
    }
}

__global__ __launch_bounds__(256) void cast_w(const float* __restrict__ wq,
                                              const float* __restrict__ wk,
                                              const float* __restrict__ wv,
                                              const float* __restrict__ wo,
                                              bf16* __restrict__ o0, bf16* __restrict__ o1,
                                              bf16* __restrict__ o2, bf16* __restrict__ o3,
                                              int n4) {
    const int sel = blockIdx.z;
    const float* src = sel == 0 ? wq : sel == 1 ? wk : sel == 2 ? wv : wo;
    bf16* dst = sel == 0 ? o0 : sel == 1 ? o1 : sel == 2 ? o2 : o3;
    const float scale = sel == 0 ? 0.125f : 1.f;
    int i = blockIdx.x * 256 + threadIdx.x;
    if (i < n4) {
        const float4 vv = ((const float4*)src)[i];
        bf16x4 o = {(bf16)(vv.x * scale), (bf16)(vv.y * scale),
                    (bf16)(vv.z * scale), (bf16)(vv.w * scale)};
        ((bf16x4*)dst)[i] = o;
    }
}

__global__ __launch_bounds__(256) void scale_vec(const float* __restrict__ s,
                                                 float* __restrict__ d, int n, float sc) {
    int i = blockIdx.x * 256 + threadIdx.x;
    if (i < n) d[i] = s[i] * sc;
}

// ---------------------------------------------------------------------------
extern "C" void kernel_launch(void* const* d_in, const int* in_sizes, int n_in,
                              void* d_out, int out_size, void* d_ws, size_t ws_size,
                              hipStream_t stream) {
    const float* query = (const float*)d_in[0];
    const float* key_  = (const float*)d_in[1];
    const float* value = (const float*)d_in[2];
    const float* Wq    = (const float*)d_in[3];
    const float* bq    = (const float*)d_in[4];
    const float* Wk    = (const float*)d_in[5];
    const float* bk    = (const float*)d_in[6];
    const float* Wv    = (const float*)d_in[7];
    const float* bv    = (const float*)d_in[8];
    const float* Wo    = (const float*)d_in[9];
    const float* bo    = (const float*)d_in[10];

    const size_t nSD = (size_t)Bc * Sc * Dc;
    const size_t nWW = (size_t)Dc * Dc;

    char* ws = (char*)d_ws;
    bf16* qbf = (bf16*)ws;              ws += nSD * 2;
    bf16* kbf = (bf16*)ws;              ws += nSD * 2;
    bf16* vbf = (bf16*)ws;              ws += nSD * 2;
    bf16* wqb = (bf16*)ws;              ws += nWW * 2;
    bf16* wkb = (bf16*)ws;              ws += nWW * 2;
    bf16* wvb = (bf16*)ws;              ws += nWW * 2;
    bf16* wob = (bf16*)ws;              ws += nWW * 2;
    bf16* Qw  = (bf16*)ws;              ws += nSD * 2;
    bf16* Kw  = (bf16*)ws;              ws += nSD * 2;
    bf16* Vtw = (bf16*)ws;              ws += nSD * 2;
    bf16* Xw  = (bf16*)ws;              ws += nSD * 2;
    float* bqs = (float*)ws;            ws += Dc * 4;

    dim3 gc3((int)(nSD / 4 / 256), 1, 3);
    cast_qkv<<<gc3, 256, 0, stream>>>(query, key_, value, qbf, kbf, vbf, (int)(nSD / 4));
    dim3 gc4((int)(nWW / 4 / 256), 1, 4);
    cast_w<<<gc4, 256, 0, stream>>>(Wq, Wk, Wv, Wo, wqb, wkb, wvb, wob, (int)(nWW / 4));
    scale_vec<<<4, 256, 0, stream>>>(bq, bqs, Dc, 0.125f);

    dim3 ggrid(Dc / 128, Bc * Sc / 128, 3);
    gemm_qkv<<<ggrid, 256, 0, stream>>>(qbf, kbf, vbf, wqb, wkb, wvb,
                                        bqs, bk, bv, Qw, Kw, Vtw);

    attn_mfma<<<(Sc / 128) * Hc * Bc, 256, 0, stream>>>(Qw, Kw, Vtw, Xw);

    dim3 gout(Dc / 128, Bc * Sc / 128);
    gemm_out_k<<<gout, 256, 0, stream>>>(Xw, wob, bo, (float*)d_out);
}